// Round 1
// baseline (2247.108 us; speedup 1.0000x reference)
//
#include <hip/hip_runtime.h>
#include <hip/hip_bf16.h>

// ---------------- problem constants ----------------
#define BB    64
#define DIMN  256
#define RESN  32
#define NSLOT 8
#define NTOKN 1024
#define HIDN  256
#define NSTEP 6          // 5 iters + 1 implicit-diff step (same forward math)
#define SCALEF 0.0625f   // 256^-0.5

// conversion table: inputs 1..31 (skip d_in[0] = big 'inputs' tensor, read raw)
constexpr int kNConv = 31;
constexpr int kConvSizes[kNConv] = {
  131072,            // 1 init_noise
  1024, 256,         // 2 W_pos, 3 b_pos
  262144, 262144,    // 4 g_enc, 5 b_enc
  65536, 256,        // 6 W_m1, 7 b_m1
  65536, 256,        // 8 W_m2, 9 b_m2
  256, 256,          // 10 g_in, 11 b_in
  65536, 256,        // 12 Wq, 13 bq
  65536, 256,        // 14 Wk, 15 bk
  65536, 256,        // 16 Wv, 17 bv
  196608, 196608,    // 18 W_ih, 19 W_hh
  768, 768,          // 20 b_ih, 21 b_hh
  256, 256, 256, 256,// 22 g_s, 23 b_s, 24 g_ff, 25 b_ff
  65536, 256,        // 26 W_f1, 27 b_f1
  65536, 256,        // 28 W_f2, 29 b_f2
  256, 256           // 30 mu, 31 sigma
};
constexpr int kConvTotal = 1513984;

struct PtrPack { const void* p[kNConv]; };

// ---------------- helpers ----------------
__device__ __forceinline__ float ldin(const void* p, long i, int isbf) {
  if (isbf) {
    unsigned u = ((const unsigned short*)p)[i];
    return __uint_as_float(u << 16);
  }
  return ((const float*)p)[i];
}

// detect input dtype: g_in is all-ones. bf16 pair -> 0x3F803F80, fp32 -> 0x3F800000
__global__ void detect_dtype(const void* gin, int* flag) {
  unsigned u = *(const unsigned*)gin;
  *flag = (u == 0x3F803F80u) ? 1 : 0;
}

// convert weights/smalls (inputs 1..31) to fp32 in ws
__global__ __launch_bounds__(256) void convert_weights(PtrPack pk, const int* __restrict__ flag,
                                                       float* __restrict__ dst) {
  int idx = blockIdx.x * 256 + threadIdx.x;
  if (idx >= kConvTotal) return;
  int off = idx, a = 0;
  while (a < kNConv - 1 && off >= kConvSizes[a]) { off -= kConvSizes[a]; ++a; }
  dst[idx] = ldin(pk.p[a], off, *flag);
}

// ---------------- encoder: pos-embed + transpose + batch stats ----------------
// grid (16, 64): (token-tile of 64, batch). A[b][t][d] = in[b][d][t] + pos(t,d)
__global__ __launch_bounds__(256) void posembed_stats(
    const void* __restrict__ in0, const int* __restrict__ flag,
    const float* __restrict__ Wpos, const float* __restrict__ bpos,
    float* __restrict__ A, float* __restrict__ partials) {
  __shared__ float lds[64 * 65];
  __shared__ float red[8];
  const int tb = blockIdx.x, b = blockIdx.y, tid = threadIdx.x;
  const int t0 = tb * 64;
  const int isbf = *flag;
  float sum = 0.f, ss = 0.f;
  for (int d0 = 0; d0 < DIMN; d0 += 64) {
    __syncthreads();
    for (int it = 0; it < 16; ++it) {
      int tt = tid & 63, dd = (tid >> 6) + it * 4;
      int t = t0 + tt, d = d0 + dd;
      float gi = (float)(t >> 5) * (1.f / 31.f);
      float gj = (float)(t & 31) * (1.f / 31.f);
      const float* wp = Wpos + d * 4;
      float pos = wp[0] * gi + wp[1] * gj + wp[2] * (1.f - gi) + wp[3] * (1.f - gj) + bpos[d];
      float v = ldin(in0, ((long)b * DIMN + d) * NTOKN + t, isbf) + pos;
      sum += v; ss += v * v;
      lds[dd * 65 + tt] = v;
    }
    __syncthreads();
    for (int it = 0; it < 16; ++it) {
      int dd = tid & 63, tt = (tid >> 6) + it * 4;
      A[((long)b * NTOKN + t0 + tt) * DIMN + d0 + dd] = lds[dd * 65 + tt];
    }
  }
  // block reduce
  for (int off = 32; off; off >>= 1) { sum += __shfl_xor(sum, off); ss += __shfl_xor(ss, off); }
  int w = tid >> 6;
  if ((tid & 63) == 0) { red[w] = sum; red[4 + w] = ss; }
  __syncthreads();
  if (tid == 0) {
    partials[((long)b * 16 + tb) * 2]     = red[0] + red[1] + red[2] + red[3];
    partials[((long)b * 16 + tb) * 2 + 1] = red[4] + red[5] + red[6] + red[7];
  }
}

__global__ void stats_reduce(const float* __restrict__ partials, float* __restrict__ stats) {
  int b = threadIdx.x;
  if (b >= BB) return;
  float s = 0.f, q = 0.f;
  for (int i = 0; i < 16; ++i) {
    s += partials[((long)b * 16 + i) * 2];
    q += partials[((long)b * 16 + i) * 2 + 1];
  }
  const float invN = 1.f / (float)(NTOKN * DIMN);
  float m = s * invN;
  float var = q * invN - m * m;
  stats[b * 2] = m;
  stats[b * 2 + 1] = rsqrtf(var + 1e-5f);
}

// A = (A - m) * inv * g_enc + b_enc   (per-batch stats, [NTOK,DIM] affine)
__global__ __launch_bounds__(256) void ln2_apply(float* __restrict__ A, const float* __restrict__ stats,
                                                 const float* __restrict__ genc, const float* __restrict__ benc) {
  long i4 = (long)blockIdx.x * 256 + threadIdx.x;  // over 4194304
  long i = i4 * 4;
  int b = (int)(i >> 18);          // / 262144
  int td = (int)(i & 262143);
  float m = stats[b * 2], inv = stats[b * 2 + 1];
  float4 x = *(const float4*)(A + i);
  float4 g = *(const float4*)(genc + td);
  float4 bb = *(const float4*)(benc + td);
  float4 y;
  y.x = (x.x - m) * inv * g.x + bb.x;
  y.y = (x.y - m) * inv * g.y + bb.y;
  y.z = (x.z - m) * inv * g.z + bb.z;
  y.w = (x.w - m) * inv * g.w + bb.w;
  *(float4*)(A + i) = y;
}

// ---------------- generic fp32 GEMM, K=256: Y = act(X @ W^T + bias) [+ res] ----------------
// X[M,256], W[N,256], Y[M,N]. grid (M/64, N/64), 256 threads, 4x4 per thread.
template <int ACT, bool HASRES>
__global__ __launch_bounds__(256) void gemm_k256(
    const float* __restrict__ X, const float* __restrict__ W,
    const float* __restrict__ bias, const float* __restrict__ res,
    float* __restrict__ Y, int N) {
  __shared__ float Xs[64 * 17];
  __shared__ float Ws[64 * 17];
  const int tid = threadIdx.x;
  const int m0 = blockIdx.x * 64, n0 = blockIdx.y * 64;
  const int tx = tid & 15, ty = tid >> 4;
  const int lr = tid >> 2;
  const int lk = (tid & 3) << 2;
  float acc[4][4] = {};
  for (int k0 = 0; k0 < 256; k0 += 16) {
    __syncthreads();
    float4 xv = *(const float4*)(X + (long)(m0 + lr) * 256 + k0 + lk);
    float4 wv = *(const float4*)(W + (long)(n0 + lr) * 256 + k0 + lk);
    Xs[lr * 17 + lk + 0] = xv.x; Xs[lr * 17 + lk + 1] = xv.y;
    Xs[lr * 17 + lk + 2] = xv.z; Xs[lr * 17 + lk + 3] = xv.w;
    Ws[lr * 17 + lk + 0] = wv.x; Ws[lr * 17 + lk + 1] = wv.y;
    Ws[lr * 17 + lk + 2] = wv.z; Ws[lr * 17 + lk + 3] = wv.w;
    __syncthreads();
#pragma unroll
    for (int kk = 0; kk < 16; ++kk) {
      float a0 = Xs[(ty * 4 + 0) * 17 + kk];
      float a1 = Xs[(ty * 4 + 1) * 17 + kk];
      float a2 = Xs[(ty * 4 + 2) * 17 + kk];
      float a3 = Xs[(ty * 4 + 3) * 17 + kk];
      float b0 = Ws[(tx * 4 + 0) * 17 + kk];
      float b1 = Ws[(tx * 4 + 1) * 17 + kk];
      float b2 = Ws[(tx * 4 + 2) * 17 + kk];
      float b3 = Ws[(tx * 4 + 3) * 17 + kk];
      acc[0][0] += a0 * b0; acc[0][1] += a0 * b1; acc[0][2] += a0 * b2; acc[0][3] += a0 * b3;
      acc[1][0] += a1 * b0; acc[1][1] += a1 * b1; acc[1][2] += a1 * b2; acc[1][3] += a1 * b3;
      acc[2][0] += a2 * b0; acc[2][1] += a2 * b1; acc[2][2] += a2 * b2; acc[2][3] += a2 * b3;
      acc[3][0] += a3 * b0; acc[3][1] += a3 * b1; acc[3][2] += a3 * b2; acc[3][3] += a3 * b3;
    }
  }
#pragma unroll
  for (int i = 0; i < 4; ++i) {
    int m = m0 + ty * 4 + i;
#pragma unroll
    for (int j = 0; j < 4; ++j) {
      int n = n0 + tx * 4 + j;
      float v = acc[i][j] + bias[n];
      if (ACT == 1) v = fmaxf(v, 0.f);
      if (HASRES) v += res[(long)m * N + n];
      Y[(long)m * N + n] = v;
    }
  }
}

// ---------------- per-row LayerNorm over 256, affine ----------------
// grid rows/4, 256 threads, one wave per row.
__global__ __launch_bounds__(256) void rowln(const float* __restrict__ X, const float* __restrict__ g,
                                             const float* __restrict__ bb, float* __restrict__ Y) {
  const int tid = threadIdx.x;
  const int lane = tid & 63;
  const long row = (long)blockIdx.x * 4 + (tid >> 6);
  float4 x = *(const float4*)(X + row * 256 + lane * 4);
  float s = x.x + x.y + x.z + x.w;
  float q = x.x * x.x + x.y * x.y + x.z * x.z + x.w * x.w;
  for (int off = 32; off; off >>= 1) { s += __shfl_xor(s, off); q += __shfl_xor(q, off); }
  float m = s * (1.f / 256.f);
  float var = q * (1.f / 256.f) - m * m;
  float inv = rsqrtf(var + 1e-5f);
  float4 gv = *(const float4*)(g + lane * 4);
  float4 bv = *(const float4*)(bb + lane * 4);
  float4 y;
  y.x = (x.x - m) * inv * gv.x + bv.x;
  y.y = (x.y - m) * inv * gv.y + bv.y;
  y.z = (x.z - m) * inv * gv.z + bv.z;
  y.w = (x.w - m) * inv * gv.w + bv.w;
  *(float4*)(Y + row * 256 + lane * 4) = y;
}

// ---------------- slots init ----------------
__global__ __launch_bounds__(256) void slots_init(const float* __restrict__ noise, const float* __restrict__ mu,
                                                  const float* __restrict__ sigma, float* __restrict__ slots) {
  long i = (long)blockIdx.x * 256 + threadIdx.x;  // 131072
  int d = (int)(i & 255);
  slots[i] = mu[d] + sigma[d] * noise[i];
}

// ---------------- dots[b][j][s] = SCALE * q[b,s,:]·k[b,j,:] ----------------
// grid (16, 64), 256 threads; q held in registers per lane; wave handles 16 tokens.
__global__ __launch_bounds__(256) void dots_kernel(const float* __restrict__ q, const float* __restrict__ k,
                                                   float* __restrict__ dots) {
  const int b = blockIdx.y, jt = blockIdx.x;
  const int tid = threadIdx.x, w = tid >> 6, lane = tid & 63;
  float4 qr[NSLOT];
#pragma unroll
  for (int s = 0; s < NSLOT; ++s)
    qr[s] = *(const float4*)(q + ((long)b * NSLOT + s) * 256 + lane * 4);
  for (int tl = 0; tl < 16; ++tl) {
    int j = jt * 64 + w * 16 + tl;
    float4 kv = *(const float4*)(k + ((long)b * NTOKN + j) * 256 + lane * 4);
    float acc[NSLOT];
#pragma unroll
    for (int s = 0; s < NSLOT; ++s)
      acc[s] = kv.x * qr[s].x + kv.y * qr[s].y + kv.z * qr[s].z + kv.w * qr[s].w;
#pragma unroll
    for (int s = 0; s < NSLOT; ++s) {
      float v = acc[s];
      for (int off = 32; off; off >>= 1) v += __shfl_xor(v, off);
      if (lane == 0) dots[((long)b * NTOKN + j) * NSLOT + s] = v * SCALEF;
    }
  }
}

// ---------------- softmax over slots (axis=1) + EPS, in place ----------------
__global__ __launch_bounds__(256) void softmax_slots(float* __restrict__ dots) {
  long t = (long)blockIdx.x * 256 + threadIdx.x;  // 0..65535 (b*NTOK+j)
  if (t >= (long)BB * NTOKN) return;
  float4 a = *(const float4*)(dots + t * 8);
  float4 c = *(const float4*)(dots + t * 8 + 4);
  float m = fmaxf(fmaxf(fmaxf(a.x, a.y), fmaxf(a.z, a.w)),
                  fmaxf(fmaxf(c.x, c.y), fmaxf(c.z, c.w)));
  float e0 = expf(a.x - m), e1 = expf(a.y - m), e2 = expf(a.z - m), e3 = expf(a.w - m);
  float e4 = expf(c.x - m), e5 = expf(c.y - m), e6 = expf(c.z - m), e7 = expf(c.w - m);
  float inv = 1.f / (e0 + e1 + e2 + e3 + e4 + e5 + e6 + e7);
  float4 o0 = make_float4(e0 * inv + 1e-8f, e1 * inv + 1e-8f, e2 * inv + 1e-8f, e3 * inv + 1e-8f);
  float4 o1 = make_float4(e4 * inv + 1e-8f, e5 * inv + 1e-8f, e6 * inv + 1e-8f, e7 * inv + 1e-8f);
  *(float4*)(dots + t * 8) = o0;
  *(float4*)(dots + t * 8 + 4) = o1;
}

// ---------------- attn row sums over tokens: asum[b][s] ----------------
__global__ __launch_bounds__(256) void attn_sum_kernel(const float* __restrict__ attn, float* __restrict__ asum) {
  __shared__ float lds[256];
  const int b = blockIdx.x, tid = threadIdx.x;
  const int i = tid & 7, g = tid >> 3;
  float acc = 0.f;
  for (int j = g; j < NTOKN; j += 32) acc += attn[((long)b * NTOKN + j) * 8 + i];
  lds[tid] = acc;
  __syncthreads();
  if (tid < 8) {
    float s = 0.f;
    for (int g2 = 0; g2 < 32; ++g2) s += lds[g2 * 8 + tid];
    asum[b * 8 + tid] = s;
  }
}

// ---------------- upd[b,s,d] = sum_j attn[b,j,s] * v[b,j,d] / asum[b,s] ----------------
// grid (4, 64): (d-chunk of 64, batch); wave w handles slots 2w, 2w+1.
__global__ __launch_bounds__(256) void upd_kernel(const float* __restrict__ attn, const float* __restrict__ asum,
                                                  const float* __restrict__ v, float* __restrict__ upd) {
  const int b = blockIdx.y, c = blockIdx.x;
  const int tid = threadIdx.x, w = tid >> 6, lane = tid & 63;
  const int d = c * 64 + lane;
  const int s0 = w * 2;
  float a0 = 0.f, a1 = 0.f;
#pragma unroll 4
  for (int j = 0; j < NTOKN; ++j) {
    float vv = v[((long)b * NTOKN + j) * 256 + d];
    const float* ar = attn + ((long)b * NTOKN + j) * 8;
    a0 += ar[s0] * vv;
    a1 += ar[s0 + 1] * vv;
  }
  upd[((long)b * 8 + s0) * 256 + d]     = a0 / asum[b * 8 + s0];
  upd[((long)b * 8 + s0 + 1) * 256 + d] = a1 / asum[b * 8 + s0 + 1];
}

// ---------------- GRU gates ----------------
__global__ __launch_bounds__(256) void gru_gates(const float* __restrict__ gi, const float* __restrict__ gh,
                                                 const float* __restrict__ slots, float* __restrict__ ns) {
  long i = (long)blockIdx.x * 256 + threadIdx.x;  // 131072
  long row = i >> 8;
  int d = (int)(i & 255);
  const float* gir = gi + row * 768;
  const float* ghr = gh + row * 768;
  float ir = gir[d], iz = gir[256 + d], in_ = gir[512 + d];
  float hr = ghr[d], hz = ghr[256 + d], hn = ghr[512 + d];
  float r = 1.f / (1.f + expf(-(ir + hr)));
  float z = 1.f / (1.f + expf(-(iz + hz)));
  float n = tanhf(in_ + r * hn);
  ns[i] = (1.f - z) * n + z * slots[i];
}

// ---------------- output write (dtype per flag) ----------------
__global__ __launch_bounds__(256) void write_out(const float* __restrict__ slots, const int* __restrict__ flag,
                                                 void* __restrict__ out) {
  long i = (long)blockIdx.x * 256 + threadIdx.x;  // 131072
  float v = slots[i];
  if (*flag) ((__hip_bfloat16*)out)[i] = __float2bfloat16(v);
  else ((float*)out)[i] = v;
}

// ---------------- host ----------------
extern "C" void kernel_launch(void* const* d_in, const int* in_sizes, int n_in,
                              void* d_out, int out_size, void* d_ws, size_t ws_size,
                              hipStream_t stream) {
  (void)in_sizes; (void)n_in; (void)out_size; (void)ws_size;
  float* wsf = (float*)d_ws;
  long o = 0;
  float* conv = wsf; o += kConvTotal;
  float* A    = wsf + o; o += (long)BB * NTOKN * DIMN;   // 16.8M
  float* Bf   = wsf + o; o += (long)BB * NTOKN * DIMN;   // k lives here
  float* Cf   = wsf + o; o += (long)BB * NTOKN * DIMN;   // v lives here
  float* slots = wsf + o; o += 131072;
  float* sln   = wsf + o; o += 131072;
  float* qb    = wsf + o; o += 131072;
  float* dots  = wsf + o; o += (long)BB * NTOKN * NSLOT; // 524288
  float* asum  = wsf + o; o += 512;
  float* updb  = wsf + o; o += 131072;
  float* gib   = wsf + o; o += 393216;
  float* ghb   = wsf + o; o += 393216;
  float* nsb   = wsf + o; o += 131072;
  float* ffl   = wsf + o; o += 131072;
  float* hbuf  = wsf + o; o += 131072;
  float* partials = wsf + o; o += 2048;
  float* stats = wsf + o; o += 128;
  int* flag = (int*)(wsf + o); o += 1;

  long coff[kNConv];
  { long acc = 0; for (int i = 0; i < kNConv; ++i) { coff[i] = acc; acc += kConvSizes[i]; } }
  const float* noise_f = conv + coff[0];
  const float* Wpos  = conv + coff[1];
  const float* bpos  = conv + coff[2];
  const float* genc  = conv + coff[3];
  const float* benc  = conv + coff[4];
  const float* Wm1   = conv + coff[5];
  const float* bm1   = conv + coff[6];
  const float* Wm2   = conv + coff[7];
  const float* bm2   = conv + coff[8];
  const float* gin   = conv + coff[9];
  const float* bin   = conv + coff[10];
  const float* Wq    = conv + coff[11];
  const float* bq    = conv + coff[12];
  const float* Wk    = conv + coff[13];
  const float* bk    = conv + coff[14];
  const float* Wv    = conv + coff[15];
  const float* bv    = conv + coff[16];
  const float* Wih   = conv + coff[17];
  const float* Whh   = conv + coff[18];
  const float* bih   = conv + coff[19];
  const float* bhh   = conv + coff[20];
  const float* gs    = conv + coff[21];
  const float* bs    = conv + coff[22];
  const float* gff   = conv + coff[23];
  const float* bff   = conv + coff[24];
  const float* Wf1   = conv + coff[25];
  const float* bf1   = conv + coff[26];
  const float* Wf2   = conv + coff[27];
  const float* bf2   = conv + coff[28];
  const float* mu    = conv + coff[29];
  const float* sigma = conv + coff[30];

  // 1. dtype probe (g_in = d_in[10] is all-ones)
  detect_dtype<<<1, 1, 0, stream>>>(d_in[10], flag);

  // 2. convert weights to fp32
  PtrPack pk;
  for (int i = 0; i < kNConv; ++i) pk.p[i] = d_in[i + 1];
  convert_weights<<<kConvTotal / 256, 256, 0, stream>>>(pk, flag, conv);

  // 3. encoder
  posembed_stats<<<dim3(16, 64), 256, 0, stream>>>(d_in[0], flag, Wpos, bpos, A, partials);
  stats_reduce<<<1, 64, 0, stream>>>(partials, stats);
  ln2_apply<<<16384, 256, 0, stream>>>(A, stats, genc, benc);
  const int MT = BB * NTOKN / 64;  // 1024 m-tiles
  gemm_k256<1, false><<<dim3(MT, 4), 256, 0, stream>>>(A, Wm1, bm1, nullptr, Bf, 256);
  gemm_k256<1, false><<<dim3(MT, 4), 256, 0, stream>>>(Bf, Wm2, bm2, nullptr, A, 256);
  rowln<<<BB * NTOKN / 4, 256, 0, stream>>>(A, gin, bin, A);
  gemm_k256<0, false><<<dim3(MT, 4), 256, 0, stream>>>(A, Wk, bk, nullptr, Bf, 256);  // k
  gemm_k256<0, false><<<dim3(MT, 4), 256, 0, stream>>>(A, Wv, bv, nullptr, Cf, 256);  // v

  // 4. slots init
  slots_init<<<512, 256, 0, stream>>>(noise_f, mu, sigma, slots);

  // 5. iterations
  for (int it = 0; it < NSTEP; ++it) {
    rowln<<<128, 256, 0, stream>>>(slots, gs, bs, sln);
    gemm_k256<0, false><<<dim3(8, 4), 256, 0, stream>>>(sln, Wq, bq, nullptr, qb, 256);
    dots_kernel<<<dim3(16, 64), 256, 0, stream>>>(qb, Bf, dots);
    softmax_slots<<<256, 256, 0, stream>>>(dots);
    attn_sum_kernel<<<64, 256, 0, stream>>>(dots, asum);
    upd_kernel<<<dim3(4, 64), 256, 0, stream>>>(dots, asum, Cf, updb);
    gemm_k256<0, false><<<dim3(8, 12), 256, 0, stream>>>(updb, Wih, bih, nullptr, gib, 768);
    gemm_k256<0, false><<<dim3(8, 12), 256, 0, stream>>>(slots, Whh, bhh, nullptr, ghb, 768);
    gru_gates<<<512, 256, 0, stream>>>(gib, ghb, slots, nsb);
    rowln<<<128, 256, 0, stream>>>(nsb, gff, bff, ffl);
    gemm_k256<1, false><<<dim3(8, 4), 256, 0, stream>>>(ffl, Wf1, bf1, nullptr, hbuf, 256);
    gemm_k256<0, true><<<dim3(8, 4), 256, 0, stream>>>(hbuf, Wf2, bf2, nsb, slots, 256);
  }

  // 6. output
  write_out<<<512, 256, 0, stream>>>(slots, flag, d_out);
}

// Round 2
// 1655.836 us; speedup vs baseline: 1.3571x; 1.3571x over previous
//
#include <hip/hip_runtime.h>
#include <hip/hip_bf16.h>

// ---------------- problem constants ----------------
#define BB    64
#define DIMN  256
#define NSLOT 8
#define NTOKN 1024
#define NSTEP 6
#define SCALEF 0.0625f

typedef __attribute__((ext_vector_type(8))) short short8;
typedef __attribute__((ext_vector_type(8))) unsigned short ushort8;
typedef __attribute__((ext_vector_type(4))) unsigned short ushort4v;
typedef __attribute__((ext_vector_type(4))) float f32x4;

__device__ __forceinline__ float b2f(unsigned short u) {
  return __uint_as_float((unsigned)u << 16);
}
__device__ __forceinline__ unsigned short f2b(float f) {
  unsigned u = __float_as_uint(f);
  return (unsigned short)((u + 0x7FFFu + ((u >> 16) & 1u)) >> 16);
}

// conversion table: inputs 1..31
constexpr int kNConv = 31;
constexpr int kConvSizes[kNConv] = {
  131072, 1024, 256, 262144, 262144, 65536, 256, 65536, 256, 256, 256,
  65536, 256, 65536, 256, 65536, 256, 196608, 196608, 768, 768,
  256, 256, 256, 256, 65536, 256, 65536, 256, 256, 256
};
constexpr int kConvTotal = 1513984;

struct PtrPack { const void* p[kNConv]; };

__device__ __forceinline__ float ldin(const void* p, long i, int isbf) {
  if (isbf) return b2f(((const unsigned short*)p)[i]);
  return ((const float*)p)[i];
}

__global__ void detect_dtype(const void* gin, int* flag) {
  unsigned u = *(const unsigned*)gin;
  *flag = (u == 0x3F803F80u) ? 1 : 0;
}

__global__ __launch_bounds__(256) void convert_weights(PtrPack pk, const int* __restrict__ flag,
                                                       float* __restrict__ dst) {
  int idx = blockIdx.x * 256 + threadIdx.x;
  if (idx >= kConvTotal) return;
  int off = idx, a = 0;
  while (a < kNConv - 1 && off >= kConvSizes[a]) { off -= kConvSizes[a]; ++a; }
  dst[idx] = ldin(pk.p[a], off, *flag);
}

// bf16 copies of the 9 GEMM weight matrices (dst contiguous)
constexpr int kWN = 9;
constexpr int kWSize[kWN]  = {65536, 65536, 65536, 65536, 65536, 196608, 196608, 65536, 65536};
constexpr int kWSrc[kWN]   = {656640, 722432, 788736, 854528, 920320, 986112, 1182720, 1381888, 1447680};
constexpr int kWTotal = 851968;

__global__ __launch_bounds__(256) void convert_wbf16(const float* __restrict__ conv,
                                                     unsigned short* __restrict__ wbf) {
  int idx = blockIdx.x * 256 + threadIdx.x;
  if (idx >= kWTotal) return;
  int off = idx, m = 0;
  while (m < kWN - 1 && off >= kWSize[m]) { off -= kWSize[m]; ++m; }
  wbf[idx] = f2b(conv[kWSrc[m] + off]);
}

// ---------------- encoder: pos-embed + transpose (bf16 out) + batch stats ----------------
__global__ __launch_bounds__(256) void posembed_stats(
    const void* __restrict__ in0, const int* __restrict__ flag,
    const float* __restrict__ Wpos, const float* __restrict__ bpos,
    unsigned short* __restrict__ A, float* __restrict__ partials) {
  __shared__ float lds[64 * 65];
  __shared__ float red[8];
  const int tb = blockIdx.x, b = blockIdx.y, tid = threadIdx.x;
  const int t0 = tb * 64;
  const int isbf = *flag;
  float sum = 0.f, ss = 0.f;
  for (int d0 = 0; d0 < DIMN; d0 += 64) {
    __syncthreads();
    for (int it = 0; it < 16; ++it) {
      int tt = tid & 63, dd = (tid >> 6) + it * 4;
      int t = t0 + tt, d = d0 + dd;
      float gi = (float)(t >> 5) * (1.f / 31.f);
      float gj = (float)(t & 31) * (1.f / 31.f);
      const float* wp = Wpos + d * 4;
      float pos = wp[0] * gi + wp[1] * gj + wp[2] * (1.f - gi) + wp[3] * (1.f - gj) + bpos[d];
      float v = ldin(in0, ((long)b * DIMN + d) * NTOKN + t, isbf) + pos;
      sum += v; ss += v * v;
      lds[dd * 65 + tt] = v;
    }
    __syncthreads();
    for (int it = 0; it < 16; ++it) {
      int dd = tid & 63, tt = (tid >> 6) + it * 4;
      A[((long)b * NTOKN + t0 + tt) * DIMN + d0 + dd] = f2b(lds[dd * 65 + tt]);
    }
  }
  for (int off = 32; off; off >>= 1) { sum += __shfl_xor(sum, off); ss += __shfl_xor(ss, off); }
  int w = tid >> 6;
  if ((tid & 63) == 0) { red[w] = sum; red[4 + w] = ss; }
  __syncthreads();
  if (tid == 0) {
    partials[((long)b * 16 + tb) * 2]     = red[0] + red[1] + red[2] + red[3];
    partials[((long)b * 16 + tb) * 2 + 1] = red[4] + red[5] + red[6] + red[7];
  }
}

__global__ void stats_reduce(const float* __restrict__ partials, float* __restrict__ stats) {
  int b = threadIdx.x;
  if (b >= BB) return;
  float s = 0.f, q = 0.f;
  for (int i = 0; i < 16; ++i) {
    s += partials[((long)b * 16 + i) * 2];
    q += partials[((long)b * 16 + i) * 2 + 1];
  }
  const float invN = 1.f / (float)(NTOKN * DIMN);
  float m = s * invN;
  float var = q * invN - m * m;
  stats[b * 2] = m;
  stats[b * 2 + 1] = rsqrtf(var + 1e-5f);
}

// in-place LN2 affine on bf16 A
__global__ __launch_bounds__(256) void ln2_apply(unsigned short* __restrict__ A, const float* __restrict__ stats,
                                                 const float* __restrict__ genc, const float* __restrict__ benc) {
  long i8 = (long)blockIdx.x * 256 + threadIdx.x;  // over 2097152
  long i = i8 * 8;
  int b = (int)(i >> 18);
  int td = (int)(i & 262143);
  float m = stats[b * 2], inv = stats[b * 2 + 1];
  ushort8 x = *(const ushort8*)(A + i);
  ushort8 y;
#pragma unroll
  for (int e = 0; e < 8; ++e) {
    float v = (b2f(x[e]) - m) * inv * genc[td + e] + benc[td + e];
    y[e] = f2b(v);
  }
  *(ushort8*)(A + i) = y;
}

// ---------------- bf16 MFMA GEMM, K=256: Y = act(X @ W^T + bias) [+res] ----------------
// X[M,256] bf16, W[N,256] bf16 (read direct from global, L1/L2-resident),
// grid (M/64, N/256), 256 threads = 4 waves, wave computes 16 rows x 256 cols.
template <int ACT, bool HASRES, bool OUTBF>
__global__ __launch_bounds__(256) void gemm_mfma(
    const unsigned short* __restrict__ X, const unsigned short* __restrict__ W,
    const float* __restrict__ bias, const float* __restrict__ res,
    void* __restrict__ Y, int N) {
  __shared__ unsigned short Xs[64 * 264];   // row stride 264 bf16 = 528 B
  const int tid = threadIdx.x;
  const int m0 = blockIdx.x * 64;
  const int n_base = blockIdx.y * 256;
  // stage X tile 64x256 bf16
#pragma unroll
  for (int i = 0; i < 8; ++i) {
    int c = tid + i * 256;          // 2048 chunks of 16B
    int row = c >> 5, seg = c & 31;
    *(ushort8*)&Xs[row * 264 + seg * 8] =
        *(const ushort8*)(X + (long)(m0 + row) * 256 + seg * 8);
  }
  __syncthreads();
  const int wave = tid >> 6, lane = tid & 63;
  const int lrow = lane & 15, kgrp = lane >> 4;
  short8 a[8];
#pragma unroll
  for (int kc = 0; kc < 8; ++kc)
    a[kc] = *(const short8*)&Xs[(wave * 16 + lrow) * 264 + kc * 32 + kgrp * 8];
#pragma unroll 2
  for (int nt = 0; nt < 16; ++nt) {
    const int n = n_base + nt * 16 + lrow;
    const unsigned short* wp = W + (long)n * 256 + kgrp * 8;
    f32x4 acc = {0.f, 0.f, 0.f, 0.f};
#pragma unroll
    for (int kc = 0; kc < 8; ++kc) {
      short8 w8 = *(const short8*)(wp + kc * 32);
      acc = __builtin_amdgcn_mfma_f32_16x16x32_bf16(a[kc], w8, acc, 0, 0, 0);
    }
    float bsn = bias[n];
#pragma unroll
    for (int r = 0; r < 4; ++r) {
      int m = m0 + wave * 16 + kgrp * 4 + r;
      float v = acc[r] + bsn;
      if (ACT == 1) v = fmaxf(v, 0.f);
      if (HASRES) v += res[(long)m * N + n];
      if (OUTBF) ((unsigned short*)Y)[(long)m * N + n] = f2b(v);
      else       ((float*)Y)[(long)m * N + n] = v;
    }
  }
}

// ---------------- per-row LayerNorm over 256, bf16 in/out ----------------
__global__ __launch_bounds__(256) void rowln_bf(const unsigned short* __restrict__ X,
                                                const float* __restrict__ g, const float* __restrict__ bb,
                                                unsigned short* __restrict__ Y) {
  const int tid = threadIdx.x, lane = tid & 63;
  const long row = (long)blockIdx.x * 4 + (tid >> 6);
  ushort4v xv = *(const ushort4v*)(X + row * 256 + lane * 4);
  float x0 = b2f(xv[0]), x1 = b2f(xv[1]), x2 = b2f(xv[2]), x3 = b2f(xv[3]);
  float s = x0 + x1 + x2 + x3;
  float q = x0 * x0 + x1 * x1 + x2 * x2 + x3 * x3;
  for (int off = 32; off; off >>= 1) { s += __shfl_xor(s, off); q += __shfl_xor(q, off); }
  float m = s * (1.f / 256.f);
  float inv = rsqrtf(q * (1.f / 256.f) - m * m + 1e-5f);
  float4 gv = *(const float4*)(g + lane * 4);
  float4 bv = *(const float4*)(bb + lane * 4);
  ushort4v y;
  y[0] = f2b((x0 - m) * inv * gv.x + bv.x);
  y[1] = f2b((x1 - m) * inv * gv.y + bv.y);
  y[2] = f2b((x2 - m) * inv * gv.z + bv.z);
  y[3] = f2b((x3 - m) * inv * gv.w + bv.w);
  *(ushort4v*)(Y + row * 256 + lane * 4) = y;
}

// ---------------- slots init ----------------
__global__ __launch_bounds__(256) void slots_init(const float* __restrict__ noise, const float* __restrict__ mu,
                                                  const float* __restrict__ sigma, float* __restrict__ slots) {
  long i = (long)blockIdx.x * 256 + threadIdx.x;
  int d = (int)(i & 255);
  slots[i] = mu[d] + sigma[d] * noise[i];
}

// ---------------- lnq: LN(slots)->sln bf16, slots->sbf bf16, zero asum ----------------
__global__ __launch_bounds__(256) void lnq_kernel(const float* __restrict__ slots,
                                                  const float* __restrict__ g, const float* __restrict__ bb,
                                                  unsigned short* __restrict__ sln,
                                                  unsigned short* __restrict__ sbf,
                                                  float* __restrict__ asum) {
  const int tid = threadIdx.x, lane = tid & 63;
  if (blockIdx.x < 2) asum[blockIdx.x * 256 + tid] = 0.f;
  const long row = (long)blockIdx.x * 4 + (tid >> 6);
  float4 x = *(const float4*)(slots + row * 256 + lane * 4);
  float s = x.x + x.y + x.z + x.w;
  float q = x.x * x.x + x.y * x.y + x.z * x.z + x.w * x.w;
  for (int off = 32; off; off >>= 1) { s += __shfl_xor(s, off); q += __shfl_xor(q, off); }
  float m = s * (1.f / 256.f);
  float inv = rsqrtf(q * (1.f / 256.f) - m * m + 1e-5f);
  float4 gv = *(const float4*)(g + lane * 4);
  float4 bv = *(const float4*)(bb + lane * 4);
  ushort4v y, rb;
  y[0] = f2b((x.x - m) * inv * gv.x + bv.x);
  y[1] = f2b((x.y - m) * inv * gv.y + bv.y);
  y[2] = f2b((x.z - m) * inv * gv.z + bv.z);
  y[3] = f2b((x.w - m) * inv * gv.w + bv.w);
  rb[0] = f2b(x.x); rb[1] = f2b(x.y); rb[2] = f2b(x.z); rb[3] = f2b(x.w);
  *(ushort4v*)(sln + row * 256 + lane * 4) = y;
  *(ushort4v*)(sbf + row * 256 + lane * 4) = rb;
}

// ---------------- fused dots + softmax-over-slots + asum atomics ----------------
__global__ __launch_bounds__(256) void attn1(const unsigned short* __restrict__ qb,
                                             const unsigned short* __restrict__ kb,
                                             float* __restrict__ attn, float* __restrict__ asum) {
  __shared__ float red[4][8];
  const int b = blockIdx.y, jt = blockIdx.x;
  const int tid = threadIdx.x, w = tid >> 6, lane = tid & 63;
  float4 qr[NSLOT];
#pragma unroll
  for (int s = 0; s < NSLOT; ++s) {
    ushort4v t4 = *(const ushort4v*)(qb + ((long)b * NSLOT + s) * 256 + lane * 4);
    qr[s] = make_float4(b2f(t4[0]), b2f(t4[1]), b2f(t4[2]), b2f(t4[3]));
  }
  float lsum[NSLOT] = {0.f, 0.f, 0.f, 0.f, 0.f, 0.f, 0.f, 0.f};
  for (int tl = 0; tl < 16; ++tl) {
    int j = jt * 64 + w * 16 + tl;
    ushort4v kv4 = *(const ushort4v*)(kb + ((long)(b * NTOKN + j)) * 256 + lane * 4);
    float k0 = b2f(kv4[0]), k1 = b2f(kv4[1]), k2 = b2f(kv4[2]), k3 = b2f(kv4[3]);
    float acc[NSLOT];
#pragma unroll
    for (int s = 0; s < NSLOT; ++s)
      acc[s] = k0 * qr[s].x + k1 * qr[s].y + k2 * qr[s].z + k3 * qr[s].w;
#pragma unroll
    for (int s = 0; s < NSLOT; ++s)
      for (int off = 32; off; off >>= 1) acc[s] += __shfl_xor(acc[s], off);
    if (lane == 0) {
      float mx = acc[0];
#pragma unroll
      for (int s = 1; s < NSLOT; ++s) mx = fmaxf(mx, acc[s]);
      float e[NSLOT], den = 0.f;
#pragma unroll
      for (int s = 0; s < NSLOT; ++s) { e[s] = expf(acc[s] * SCALEF - mx * SCALEF); den += e[s]; }
      float invd = 1.f / den;
      float4 o0, o1;
      o0.x = e[0] * invd + 1e-8f; o0.y = e[1] * invd + 1e-8f;
      o0.z = e[2] * invd + 1e-8f; o0.w = e[3] * invd + 1e-8f;
      o1.x = e[4] * invd + 1e-8f; o1.y = e[5] * invd + 1e-8f;
      o1.z = e[6] * invd + 1e-8f; o1.w = e[7] * invd + 1e-8f;
      float* ap = attn + ((long)(b * NTOKN + j)) * 8;
      *(float4*)ap = o0; *(float4*)(ap + 4) = o1;
      lsum[0] += o0.x; lsum[1] += o0.y; lsum[2] += o0.z; lsum[3] += o0.w;
      lsum[4] += o1.x; lsum[5] += o1.y; lsum[6] += o1.z; lsum[7] += o1.w;
    }
  }
  if (lane == 0)
#pragma unroll
    for (int s = 0; s < NSLOT; ++s) red[w][s] = lsum[s];
  __syncthreads();
  if (tid < NSLOT) {
    float t = red[0][tid] + red[1][tid] + red[2][tid] + red[3][tid];
    atomicAdd(&asum[b * NSLOT + tid], t);
  }
}

// ---------------- upd[b,s,d] = sum_j attn[b,j,s]*v[b,j,d] / asum[b,s], bf16 out ----------------
__global__ __launch_bounds__(256) void upd_kernel(const float* __restrict__ attn, const float* __restrict__ asum,
                                                  const unsigned short* __restrict__ v,
                                                  unsigned short* __restrict__ upd) {
  const int b = blockIdx.y, c = blockIdx.x;
  const int tid = threadIdx.x, w = tid >> 6, lane = tid & 63;
  const int d = c * 64 + lane;
  const int s0 = w * 2;
  float a0 = 0.f, a1 = 0.f;
#pragma unroll 4
  for (int j = 0; j < NTOKN; ++j) {
    float vv = b2f(v[((long)(b * NTOKN + j)) * 256 + d]);
    const float* ar = attn + ((long)(b * NTOKN + j)) * 8;
    a0 += ar[s0] * vv;
    a1 += ar[s0 + 1] * vv;
  }
  upd[((long)b * 8 + s0) * 256 + d]     = f2b(a0 / asum[b * 8 + s0]);
  upd[((long)b * 8 + s0 + 1) * 256 + d] = f2b(a1 / asum[b * 8 + s0 + 1]);
}

// ---------------- GRU gates + LN(g_ff) fused: ns fp32, ffl bf16 ----------------
__global__ __launch_bounds__(256) void gru_ln(const float* __restrict__ gi, const float* __restrict__ gh,
                                              const float* __restrict__ slots,
                                              const float* __restrict__ gff, const float* __restrict__ bff,
                                              float* __restrict__ ns, unsigned short* __restrict__ ffl) {
  const int tid = threadIdx.x, lane = tid & 63;
  const long row = (long)blockIdx.x * 4 + (tid >> 6);
  const int d = lane * 4;
  float4 i1 = *(const float4*)(gi + row * 768 + d);
  float4 i2 = *(const float4*)(gi + row * 768 + 256 + d);
  float4 i3 = *(const float4*)(gi + row * 768 + 512 + d);
  float4 h1 = *(const float4*)(gh + row * 768 + d);
  float4 h2 = *(const float4*)(gh + row * 768 + 256 + d);
  float4 h3 = *(const float4*)(gh + row * 768 + 512 + d);
  float4 sl = *(const float4*)(slots + row * 256 + d);
  float n4[4];
  float r, z, nn;
  r = 1.f / (1.f + expf(-(i1.x + h1.x))); z = 1.f / (1.f + expf(-(i2.x + h2.x)));
  nn = tanhf(i3.x + r * h3.x); n4[0] = (1.f - z) * nn + z * sl.x;
  r = 1.f / (1.f + expf(-(i1.y + h1.y))); z = 1.f / (1.f + expf(-(i2.y + h2.y)));
  nn = tanhf(i3.y + r * h3.y); n4[1] = (1.f - z) * nn + z * sl.y;
  r = 1.f / (1.f + expf(-(i1.z + h1.z))); z = 1.f / (1.f + expf(-(i2.z + h2.z)));
  nn = tanhf(i3.z + r * h3.z); n4[2] = (1.f - z) * nn + z * sl.z;
  r = 1.f / (1.f + expf(-(i1.w + h1.w))); z = 1.f / (1.f + expf(-(i2.w + h2.w)));
  nn = tanhf(i3.w + r * h3.w); n4[3] = (1.f - z) * nn + z * sl.w;
  *(float4*)(ns + row * 256 + d) = make_float4(n4[0], n4[1], n4[2], n4[3]);
  float s = n4[0] + n4[1] + n4[2] + n4[3];
  float q = n4[0] * n4[0] + n4[1] * n4[1] + n4[2] * n4[2] + n4[3] * n4[3];
  for (int off = 32; off; off >>= 1) { s += __shfl_xor(s, off); q += __shfl_xor(q, off); }
  float m = s * (1.f / 256.f);
  float inv = rsqrtf(q * (1.f / 256.f) - m * m + 1e-5f);
  float4 gv = *(const float4*)(gff + d);
  float4 bv = *(const float4*)(bff + d);
  ushort4v y;
  y[0] = f2b((n4[0] - m) * inv * gv.x + bv.x);
  y[1] = f2b((n4[1] - m) * inv * gv.y + bv.y);
  y[2] = f2b((n4[2] - m) * inv * gv.z + bv.z);
  y[3] = f2b((n4[3] - m) * inv * gv.w + bv.w);
  *(ushort4v*)(ffl + row * 256 + d) = y;
}

// ---------------- output ----------------
__global__ __launch_bounds__(256) void write_out(const float* __restrict__ slots, const int* __restrict__ flag,
                                                 void* __restrict__ out) {
  long i = (long)blockIdx.x * 256 + threadIdx.x;
  float v = slots[i];
  if (*flag) ((__hip_bfloat16*)out)[i] = __float2bfloat16(v);
  else ((float*)out)[i] = v;
}

// ---------------- host ----------------
extern "C" void kernel_launch(void* const* d_in, const int* in_sizes, int n_in,
                              void* d_out, int out_size, void* d_ws, size_t ws_size,
                              hipStream_t stream) {
  (void)in_sizes; (void)n_in; (void)out_size; (void)ws_size;
  float* wsf = (float*)d_ws;
  long o = 0;
  float* conv = wsf; o += kConvTotal;                       // fp32 weights
  unsigned short* wbf = (unsigned short*)(wsf + o); o += kWTotal / 2;  // bf16 weights
  unsigned short* A   = (unsigned short*)(wsf + o); o += (long)BB * NTOKN * DIMN / 2;
  unsigned short* X1  = (unsigned short*)(wsf + o); o += (long)BB * NTOKN * DIMN / 2;
  unsigned short* X2  = (unsigned short*)(wsf + o); o += (long)BB * NTOKN * DIMN / 2;
  unsigned short* Kb  = (unsigned short*)(wsf + o); o += (long)BB * NTOKN * DIMN / 2;
  unsigned short* Vb  = (unsigned short*)(wsf + o); o += (long)BB * NTOKN * DIMN / 2;
  float* slots = wsf + o; o += 131072;
  unsigned short* sln = (unsigned short*)(wsf + o); o += 65536;
  unsigned short* sbf = (unsigned short*)(wsf + o); o += 65536;
  unsigned short* qb  = (unsigned short*)(wsf + o); o += 65536;
  float* dots  = wsf + o; o += (long)BB * NTOKN * NSLOT;
  float* asum  = wsf + o; o += 512;
  unsigned short* updb = (unsigned short*)(wsf + o); o += 65536;
  float* gib   = wsf + o; o += 393216;
  float* ghb   = wsf + o; o += 393216;
  float* nsb   = wsf + o; o += 131072;
  unsigned short* ffl  = (unsigned short*)(wsf + o); o += 65536;
  unsigned short* hbuf = (unsigned short*)(wsf + o); o += 65536;
  float* partials = wsf + o; o += 2048;
  float* stats = wsf + o; o += 128;
  int* flag = (int*)(wsf + o); o += 16;

  long coff[kNConv];
  { long acc = 0; for (int i = 0; i < kNConv; ++i) { coff[i] = acc; acc += kConvSizes[i]; } }
  const float* noise_f = conv + coff[0];
  const float* Wpos = conv + coff[1];
  const float* bpos = conv + coff[2];
  const float* genc = conv + coff[3];
  const float* benc = conv + coff[4];
  const float* bm1  = conv + coff[6];
  const float* bm2  = conv + coff[8];
  const float* gin  = conv + coff[9];
  const float* bin  = conv + coff[10];
  const float* bq   = conv + coff[12];
  const float* bk   = conv + coff[14];
  const float* bv   = conv + coff[16];
  const float* bih  = conv + coff[19];
  const float* bhh  = conv + coff[20];
  const float* gs   = conv + coff[21];
  const float* bs   = conv + coff[22];
  const float* gff  = conv + coff[23];
  const float* bff  = conv + coff[24];
  const float* bf1  = conv + coff[26];
  const float* bf2  = conv + coff[28];
  const float* mu   = conv + coff[29];
  const float* sigma = conv + coff[30];

  // bf16 weight views (contiguous in wbf, order per kWSrc)
  const unsigned short* Wm1b = wbf;
  const unsigned short* Wm2b = wbf + 65536;
  const unsigned short* Wqb  = wbf + 131072;
  const unsigned short* Wkb  = wbf + 196608;
  const unsigned short* Wvb  = wbf + 262144;
  const unsigned short* Wihb = wbf + 327680;
  const unsigned short* Whhb = wbf + 524288;
  const unsigned short* Wf1b = wbf + 720896;
  const unsigned short* Wf2b = wbf + 786432;

  detect_dtype<<<1, 1, 0, stream>>>(d_in[10], flag);

  PtrPack pk;
  for (int i = 0; i < kNConv; ++i) pk.p[i] = d_in[i + 1];
  convert_weights<<<(kConvTotal + 255) / 256, 256, 0, stream>>>(pk, flag, conv);
  convert_wbf16<<<(kWTotal + 255) / 256, 256, 0, stream>>>(conv, wbf);

  // encoder
  posembed_stats<<<dim3(16, 64), 256, 0, stream>>>(d_in[0], flag, Wpos, bpos, A, partials);
  stats_reduce<<<1, 64, 0, stream>>>(partials, stats);
  ln2_apply<<<8192, 256, 0, stream>>>(A, stats, genc, benc);
  const int MT = BB * NTOKN / 64;  // 1024
  gemm_mfma<1, false, true><<<dim3(MT, 1), 256, 0, stream>>>(A,  Wm1b, bm1, nullptr, X1, 256);
  gemm_mfma<1, false, true><<<dim3(MT, 1), 256, 0, stream>>>(X1, Wm2b, bm2, nullptr, X2, 256);
  rowln_bf<<<BB * NTOKN / 4, 256, 0, stream>>>(X2, gin, bin, X2);
  gemm_mfma<0, false, true><<<dim3(MT, 1), 256, 0, stream>>>(X2, Wkb, bk, nullptr, Kb, 256);
  gemm_mfma<0, false, true><<<dim3(MT, 1), 256, 0, stream>>>(X2, Wvb, bv, nullptr, Vb, 256);

  slots_init<<<512, 256, 0, stream>>>(noise_f, mu, sigma, slots);

  for (int it = 0; it < NSTEP; ++it) {
    lnq_kernel<<<128, 256, 0, stream>>>(slots, gs, bs, sln, sbf, asum);
    gemm_mfma<0, false, true><<<dim3(8, 1), 256, 0, stream>>>(sln, Wqb, bq, nullptr, qb, 256);
    attn1<<<dim3(16, 64), 256, 0, stream>>>(qb, Kb, dots, asum);
    upd_kernel<<<dim3(4, 64), 256, 0, stream>>>(dots, asum, Vb, updb);
    gemm_mfma<0, false, false><<<dim3(8, 3), 256, 0, stream>>>(updb, Wihb, bih, nullptr, gib, 768);
    gemm_mfma<0, false, false><<<dim3(8, 3), 256, 0, stream>>>(sbf,  Whhb, bhh, nullptr, ghb, 768);
    gru_ln<<<128, 256, 0, stream>>>(gib, ghb, slots, gff, bff, nsb, ffl);
    gemm_mfma<1, false, true><<<dim3(8, 1), 256, 0, stream>>>(ffl, Wf1b, bf1, nullptr, hbuf, 256);
    gemm_mfma<0, true, false><<<dim3(8, 1), 256, 0, stream>>>(hbuf, Wf2b, bf2, nsb, slots, 256);
  }

  write_out<<<512, 256, 0, stream>>>(slots, flag, d_out);
}

// Round 4
// 865.181 us; speedup vs baseline: 2.5973x; 1.9139x over previous
//
#include <hip/hip_runtime.h>
#include <hip/hip_bf16.h>

// ---------------- problem constants ----------------
#define BB    64
#define DIMN  256
#define NSLOT 8
#define NTOKN 1024
#define NSTEP 6
#define SCALEF 0.0625f

typedef __attribute__((ext_vector_type(8))) short short8;
typedef __attribute__((ext_vector_type(8))) unsigned short ushort8;
typedef __attribute__((ext_vector_type(4))) unsigned short ushort4v;
typedef __attribute__((ext_vector_type(4))) float f32x4;

__device__ __forceinline__ float b2f(unsigned short u) {
  return __uint_as_float((unsigned)u << 16);
}
__device__ __forceinline__ unsigned short f2b(float f) {
  unsigned u = __float_as_uint(f);
  return (unsigned short)((u + 0x7FFFu + ((u >> 16) & 1u)) >> 16);
}

// conversion table: inputs 1..31
constexpr int kNConv = 31;
constexpr int kConvSizes[kNConv] = {
  131072, 1024, 256, 262144, 262144, 65536, 256, 65536, 256, 256, 256,
  65536, 256, 65536, 256, 65536, 256, 196608, 196608, 768, 768,
  256, 256, 256, 256, 65536, 256, 65536, 256, 256, 256
};
constexpr int kConvTotal = 1513984;

struct PtrPack { const void* p[kNConv]; };

__device__ __forceinline__ float ldin(const void* p, long i, int isbf) {
  if (isbf) return b2f(((const unsigned short*)p)[i]);
  return ((const float*)p)[i];
}

__global__ void detect_dtype(const void* gin, int* flag) {
  unsigned u = *(const unsigned*)gin;
  *flag = (u == 0x3F803F80u) ? 1 : 0;
}

__global__ __launch_bounds__(256) void convert_weights(PtrPack pk, const int* __restrict__ flag,
                                                       float* __restrict__ dst) {
  int idx = blockIdx.x * 256 + threadIdx.x;
  if (idx >= kConvTotal) return;
  int off = idx, a = 0;
  while (a < kNConv - 1 && off >= kConvSizes[a]) { off -= kConvSizes[a]; ++a; }
  dst[idx] = ldin(pk.p[a], off, *flag);
}

// bf16 copies of the 9 GEMM weight matrices
constexpr int kWN = 9;
constexpr int kWSize[kWN]  = {65536, 65536, 65536, 65536, 65536, 196608, 196608, 65536, 65536};
constexpr int kWSrc[kWN]   = {656640, 722432, 788736, 854528, 920320, 986112, 1182720, 1381888, 1447680};
constexpr int kWTotal = 851968;

__global__ __launch_bounds__(256) void convert_wbf16(const float* __restrict__ conv,
                                                     unsigned short* __restrict__ wbf) {
  int idx = blockIdx.x * 256 + threadIdx.x;
  if (idx >= kWTotal) return;
  int off = idx, m = 0;
  while (m < kWN - 1 && off >= kWSize[m]) { off -= kWSize[m]; ++m; }
  wbf[idx] = f2b(conv[kWSrc[m] + off]);
}

// ---------------- encoder: pos-embed + transpose (bf16 out) + batch stats ----------------
__global__ __launch_bounds__(256) void posembed_stats(
    const void* __restrict__ in0, const int* __restrict__ flag,
    const float* __restrict__ Wpos, const float* __restrict__ bpos,
    unsigned short* __restrict__ A, float* __restrict__ partials) {
  __shared__ float lds[64 * 65];
  __shared__ float red[8];
  const int tb = blockIdx.x, b = blockIdx.y, tid = threadIdx.x;
  const int t0 = tb * 64;
  const int isbf = *flag;
  float sum = 0.f, ss = 0.f;
  for (int d0 = 0; d0 < DIMN; d0 += 64) {
    __syncthreads();
    for (int it = 0; it < 16; ++it) {
      int tt = tid & 63, dd = (tid >> 6) + it * 4;
      int t = t0 + tt, d = d0 + dd;
      float gi = (float)(t >> 5) * (1.f / 31.f);
      float gj = (float)(t & 31) * (1.f / 31.f);
      const float* wp = Wpos + d * 4;
      float pos = wp[0] * gi + wp[1] * gj + wp[2] * (1.f - gi) + wp[3] * (1.f - gj) + bpos[d];
      float v = ldin(in0, ((long)b * DIMN + d) * NTOKN + t, isbf) + pos;
      sum += v; ss += v * v;
      lds[dd * 65 + tt] = v;
    }
    __syncthreads();
    for (int it = 0; it < 16; ++it) {
      int dd = tid & 63, tt = (tid >> 6) + it * 4;
      A[((long)b * NTOKN + t0 + tt) * DIMN + d0 + dd] = f2b(lds[dd * 65 + tt]);
    }
  }
  for (int off = 32; off; off >>= 1) { sum += __shfl_xor(sum, off); ss += __shfl_xor(ss, off); }
  int w = tid >> 6;
  if ((tid & 63) == 0) { red[w] = sum; red[4 + w] = ss; }
  __syncthreads();
  if (tid == 0) {
    partials[((long)b * 16 + tb) * 2]     = red[0] + red[1] + red[2] + red[3];
    partials[((long)b * 16 + tb) * 2 + 1] = red[4] + red[5] + red[6] + red[7];
  }
}

__global__ void stats_reduce(const float* __restrict__ partials, float* __restrict__ stats) {
  int b = threadIdx.x;
  if (b >= BB) return;
  float s = 0.f, q = 0.f;
  for (int i = 0; i < 16; ++i) {
    s += partials[((long)b * 16 + i) * 2];
    q += partials[((long)b * 16 + i) * 2 + 1];
  }
  const float invN = 1.f / (float)(NTOKN * DIMN);
  float m = s * invN;
  float var = q * invN - m * m;
  stats[b * 2] = m;
  stats[b * 2 + 1] = rsqrtf(var + 1e-5f);
}

// ---------------- m1: LN2-fused staging + relu GEMM -> X1 bf16 ----------------
__global__ __launch_bounds__(256) void gemm_m1(
    const unsigned short* __restrict__ A, const float* __restrict__ stats,
    const float* __restrict__ genc, const float* __restrict__ benc,
    const unsigned short* __restrict__ W, const float* __restrict__ bias,
    unsigned short* __restrict__ Y) {
  __shared__ unsigned short Xs[64 * 264];
  const int tid = threadIdx.x;
  const int m0 = blockIdx.x * 64;
#pragma unroll
  for (int i = 0; i < 8; ++i) {
    int c = tid + i * 256;
    int row = c >> 5, seg = c & 31;
    long grow = m0 + row;
    int bb_ = (int)(grow >> 10);
    int t = (int)(grow & 1023);
    float mm = stats[bb_ * 2], inv = stats[bb_ * 2 + 1];
    const float* gp = genc + (long)t * 256 + seg * 8;
    const float* bp = benc + (long)t * 256 + seg * 8;
    ushort8 raw = *(const ushort8*)(A + grow * 256 + seg * 8);
    ushort8 y;
#pragma unroll
    for (int e = 0; e < 8; ++e)
      y[e] = f2b((b2f(raw[e]) - mm) * inv * gp[e] + bp[e]);
    *(ushort8*)&Xs[row * 264 + seg * 8] = y;
  }
  __syncthreads();
  const int wave = tid >> 6, lane = tid & 63;
  const int lrow = lane & 15, kgrp = lane >> 4;
  short8 a[8];
#pragma unroll
  for (int kc = 0; kc < 8; ++kc)
    a[kc] = *(const short8*)&Xs[(wave * 16 + lrow) * 264 + kc * 32 + kgrp * 8];
#pragma unroll 2
  for (int nt = 0; nt < 16; ++nt) {
    const int n = nt * 16 + lrow;
    const unsigned short* wp = W + (long)n * 256 + kgrp * 8;
    f32x4 acc = {0.f, 0.f, 0.f, 0.f};
#pragma unroll
    for (int kc = 0; kc < 8; ++kc)
      acc = __builtin_amdgcn_mfma_f32_16x16x32_bf16(a[kc], *(const short8*)(wp + kc * 32), acc, 0, 0, 0);
    float bn = bias[n];
#pragma unroll
    for (int r = 0; r < 4; ++r) {
      int m = m0 + wave * 16 + kgrp * 4 + r;
      Y[(long)m * 256 + n] = f2b(fmaxf(acc[r] + bn, 0.f));
    }
  }
}

// ---------------- m2: relu GEMM + fused output row-LN (g_in,b_in) -> X2 bf16 ----------------
__global__ __launch_bounds__(256) void gemm_m2ln(
    const unsigned short* __restrict__ X, const unsigned short* __restrict__ W,
    const float* __restrict__ bias, const float* __restrict__ gin, const float* __restrict__ bin,
    unsigned short* __restrict__ Y) {
  __shared__ unsigned short Xs[64 * 264];
  const int tid = threadIdx.x;
  const int m0 = blockIdx.x * 64;
#pragma unroll
  for (int i = 0; i < 8; ++i) {
    int c = tid + i * 256;
    int row = c >> 5, seg = c & 31;
    *(ushort8*)&Xs[row * 264 + seg * 8] = *(const ushort8*)(X + (long)(m0 + row) * 256 + seg * 8);
  }
  __syncthreads();
  const int wave = tid >> 6, lane = tid & 63;
  const int lrow = lane & 15, kgrp = lane >> 4;
  short8 a[8];
#pragma unroll
  for (int kc = 0; kc < 8; ++kc)
    a[kc] = *(const short8*)&Xs[(wave * 16 + lrow) * 264 + kc * 32 + kgrp * 8];
  float vals[16][4];
#pragma unroll
  for (int nt = 0; nt < 16; ++nt) {
    const int n = nt * 16 + lrow;
    const unsigned short* wp = W + (long)n * 256 + kgrp * 8;
    f32x4 acc = {0.f, 0.f, 0.f, 0.f};
#pragma unroll
    for (int kc = 0; kc < 8; ++kc)
      acc = __builtin_amdgcn_mfma_f32_16x16x32_bf16(a[kc], *(const short8*)(wp + kc * 32), acc, 0, 0, 0);
    float bn = bias[n];
#pragma unroll
    for (int r = 0; r < 4; ++r) vals[nt][r] = fmaxf(acc[r] + bn, 0.f);
  }
  float sr[4] = {0.f, 0.f, 0.f, 0.f}, qr[4] = {0.f, 0.f, 0.f, 0.f};
#pragma unroll
  for (int nt = 0; nt < 16; ++nt)
#pragma unroll
    for (int r = 0; r < 4; ++r) { float v = vals[nt][r]; sr[r] += v; qr[r] += v * v; }
#pragma unroll
  for (int msk = 1; msk <= 8; msk <<= 1)
#pragma unroll
    for (int r = 0; r < 4; ++r) { sr[r] += __shfl_xor(sr[r], msk); qr[r] += __shfl_xor(qr[r], msk); }
  float mean[4], invr[4];
#pragma unroll
  for (int r = 0; r < 4; ++r) {
    mean[r] = sr[r] * (1.f / 256.f);
    invr[r] = rsqrtf(qr[r] * (1.f / 256.f) - mean[r] * mean[r] + 1e-5f);
  }
#pragma unroll
  for (int nt = 0; nt < 16; ++nt) {
    const int n = nt * 16 + lrow;
    float gn = gin[n], bn2 = bin[n];
#pragma unroll
    for (int r = 0; r < 4; ++r) {
      int m = m0 + wave * 16 + kgrp * 4 + r;
      Y[(long)m * 256 + n] = f2b((vals[nt][r] - mean[r]) * invr[r] * gn + bn2);
    }
  }
}

// ---------------- kv: one staging, two GEMMs (K and V) ----------------
__global__ __launch_bounds__(256) void gemm_kv(
    const unsigned short* __restrict__ X,
    const unsigned short* __restrict__ Wk, const unsigned short* __restrict__ Wv,
    const float* __restrict__ bk, const float* __restrict__ bv,
    unsigned short* __restrict__ Kb, unsigned short* __restrict__ Vb) {
  __shared__ unsigned short Xs[64 * 264];
  const int tid = threadIdx.x;
  const int m0 = blockIdx.x * 64;
#pragma unroll
  for (int i = 0; i < 8; ++i) {
    int c = tid + i * 256;
    int row = c >> 5, seg = c & 31;
    *(ushort8*)&Xs[row * 264 + seg * 8] = *(const ushort8*)(X + (long)(m0 + row) * 256 + seg * 8);
  }
  __syncthreads();
  const int wave = tid >> 6, lane = tid & 63;
  const int lrow = lane & 15, kgrp = lane >> 4;
  short8 a[8];
#pragma unroll
  for (int kc = 0; kc < 8; ++kc)
    a[kc] = *(const short8*)&Xs[(wave * 16 + lrow) * 264 + kc * 32 + kgrp * 8];
  for (int which = 0; which < 2; ++which) {
    const unsigned short* W = which ? Wv : Wk;
    const float* bias = which ? bv : bk;
    unsigned short* Y = which ? Vb : Kb;
#pragma unroll 2
    for (int nt = 0; nt < 16; ++nt) {
      const int n = nt * 16 + lrow;
      const unsigned short* wp = W + (long)n * 256 + kgrp * 8;
      f32x4 acc = {0.f, 0.f, 0.f, 0.f};
#pragma unroll
      for (int kc = 0; kc < 8; ++kc)
        acc = __builtin_amdgcn_mfma_f32_16x16x32_bf16(a[kc], *(const short8*)(wp + kc * 32), acc, 0, 0, 0);
      float bn = bias[n];
#pragma unroll
      for (int r = 0; r < 4; ++r) {
        int m = m0 + wave * 16 + kgrp * 4 + r;
        Y[(long)m * 256 + n] = f2b(acc[r] + bn);
      }
    }
  }
}

// ---------------- slots init ----------------
__global__ __launch_bounds__(256) void slots_init(const float* __restrict__ noise, const float* __restrict__ mu,
                                                  const float* __restrict__ sigma, float* __restrict__ slots) {
  long i = (long)blockIdx.x * 256 + threadIdx.x;
  int d = (int)(i & 255);
  slots[i] = mu[d] + sigma[d] * noise[i];
}

// ---------------- lnq_q: LN(slots) + q GEMM + slots->bf16, one block per batch ----------------
__global__ __launch_bounds__(256) void lnq_q(
    const float* __restrict__ slots, const float* __restrict__ gs, const float* __restrict__ bs,
    const unsigned short* __restrict__ Wq, const float* __restrict__ bq,
    unsigned short* __restrict__ qb, unsigned short* __restrict__ sbf) {
  __shared__ unsigned short S[16 * 264];
  const int b = blockIdx.x, tid = threadIdx.x;
  const int wave = tid >> 6, lane = tid & 63;
  for (int i = tid; i < 8 * 264; i += 256) S[8 * 264 + i] = 0;
#pragma unroll
  for (int rr = 0; rr < 2; ++rr) {
    int row = wave * 2 + rr;
    float4 xv = *(const float4*)(slots + ((long)b * 8 + row) * 256 + lane * 4);
    float s = xv.x + xv.y + xv.z + xv.w;
    float q = xv.x * xv.x + xv.y * xv.y + xv.z * xv.z + xv.w * xv.w;
    for (int off = 32; off; off >>= 1) { s += __shfl_xor(s, off); q += __shfl_xor(q, off); }
    float m = s * (1.f / 256.f);
    float inv = rsqrtf(q * (1.f / 256.f) - m * m + 1e-5f);
    float4 gv = *(const float4*)(gs + lane * 4);
    float4 bv = *(const float4*)(bs + lane * 4);
    ushort4v y, rb;
    y[0] = f2b((xv.x - m) * inv * gv.x + bv.x);
    y[1] = f2b((xv.y - m) * inv * gv.y + bv.y);
    y[2] = f2b((xv.z - m) * inv * gv.z + bv.z);
    y[3] = f2b((xv.w - m) * inv * gv.w + bv.w);
    rb[0] = f2b(xv.x); rb[1] = f2b(xv.y); rb[2] = f2b(xv.z); rb[3] = f2b(xv.w);
    *(ushort4v*)&S[row * 264 + lane * 4] = y;
    *(ushort4v*)(sbf + ((long)b * 8 + row) * 256 + lane * 4) = rb;
  }
  __syncthreads();
  const int lrow = lane & 15, kgrp = lane >> 4;
  short8 a[8];
#pragma unroll
  for (int kc = 0; kc < 8; ++kc)
    a[kc] = *(const short8*)&S[lrow * 264 + kc * 32 + kgrp * 8];
#pragma unroll
  for (int nt = 0; nt < 4; ++nt) {
    const int n = wave * 64 + nt * 16 + lrow;
    const unsigned short* wp = Wq + (long)n * 256 + kgrp * 8;
    f32x4 acc = {0.f, 0.f, 0.f, 0.f};
#pragma unroll
    for (int kc = 0; kc < 8; ++kc)
      acc = __builtin_amdgcn_mfma_f32_16x16x32_bf16(a[kc], *(const short8*)(wp + kc * 32), acc, 0, 0, 0);
    if (kgrp < 2) {
      float bn = bq[n];
#pragma unroll
      for (int r = 0; r < 4; ++r)
        qb[((long)b * 8 + kgrp * 4 + r) * 256 + n] = f2b(acc[r] + bn);
    }
  }
}

// ---------------- attn1b: MFMA dots + wave-parallel softmax + asum/upd partials ----------------
__global__ __launch_bounds__(256) void attn1b(
    const unsigned short* __restrict__ qb, const unsigned short* __restrict__ Kb,
    const unsigned short* __restrict__ Vb,
    float* __restrict__ upd_part, float* __restrict__ asum_part) {
  __shared__ unsigned short Ks[64 * 264];
  __shared__ unsigned short Qs[16 * 264];
  __shared__ float attnS[64 * 8];
  __shared__ float red[4 * 2048];
  const int jt = blockIdx.x, b = blockIdx.y, tid = threadIdx.x;
  const int wave = tid >> 6, lane = tid & 63;
#pragma unroll
  for (int i = 0; i < 8; ++i) {
    int c = tid + i * 256;
    int row = c >> 5, seg = c & 31;
    *(ushort8*)&Ks[row * 264 + seg * 8] =
        *(const ushort8*)(Kb + ((long)(b * NTOKN + jt * 64 + row)) * 256 + seg * 8);
  }
  {
    int row = tid >> 5, seg = tid & 31;
    *(ushort8*)&Qs[row * 264 + seg * 8] = *(const ushort8*)(qb + ((long)(b * 8 + row)) * 256 + seg * 8);
  }
  for (int i = tid; i < 8 * 264; i += 256) Qs[8 * 264 + i] = 0;
  __syncthreads();
  const int lrow = lane & 15, kgrp = lane >> 4;
  f32x4 acc = {0.f, 0.f, 0.f, 0.f};
#pragma unroll
  for (int kc = 0; kc < 8; ++kc) {
    short8 af = *(const short8*)&Ks[(wave * 16 + lrow) * 264 + kc * 32 + kgrp * 8];
    short8 qf = *(const short8*)&Qs[lrow * 264 + kc * 32 + kgrp * 8];
    acc = __builtin_amdgcn_mfma_f32_16x16x32_bf16(af, qf, acc, 0, 0, 0);
  }
  float t0[4], mx[4], e[4], sm[4];
#pragma unroll
  for (int r = 0; r < 4; ++r) { t0[r] = acc[r] * SCALEF; mx[r] = t0[r]; }
#pragma unroll
  for (int msk = 1; msk <= 4; msk <<= 1)
#pragma unroll
    for (int r = 0; r < 4; ++r) mx[r] = fmaxf(mx[r], __shfl_xor(mx[r], msk));
#pragma unroll
  for (int r = 0; r < 4; ++r) { e[r] = expf(t0[r] - mx[r]); sm[r] = e[r]; }
#pragma unroll
  for (int msk = 1; msk <= 4; msk <<= 1)
#pragma unroll
    for (int r = 0; r < 4; ++r) sm[r] += __shfl_xor(sm[r], msk);
  if (lrow < 8) {
#pragma unroll
    for (int r = 0; r < 4; ++r) {
      int jl = wave * 16 + kgrp * 4 + r;
      attnS[jl * 8 + lrow] = e[r] / sm[r] + 1e-8f;
    }
  }
  __syncthreads();
  {
    int s0 = wave * 2;
    float v0 = attnS[lane * 8 + s0], v1 = attnS[lane * 8 + s0 + 1];
    for (int off = 32; off; off >>= 1) { v0 += __shfl_xor(v0, off); v1 += __shfl_xor(v1, off); }
    if (lane == 0) {
      asum_part[((long)(b * 16 + jt)) * 8 + s0] = v0;
      asum_part[((long)(b * 16 + jt)) * 8 + s0 + 1] = v1;
    }
  }
  float au[8][4] = {};
  for (int jl = 0; jl < 16; ++jl) {
    int j = wave * 16 + jl;
    ushort4v v4 = *(const ushort4v*)(Vb + ((long)(b * NTOKN + jt * 64 + j)) * 256 + lane * 4);
    float v0 = b2f(v4[0]), v1 = b2f(v4[1]), v2 = b2f(v4[2]), v3 = b2f(v4[3]);
    float4 a01 = *(const float4*)&attnS[j * 8];
    float4 a23 = *(const float4*)&attnS[j * 8 + 4];
    float aw[8] = {a01.x, a01.y, a01.z, a01.w, a23.x, a23.y, a23.z, a23.w};
#pragma unroll
    for (int s = 0; s < 8; ++s) {
      au[s][0] += aw[s] * v0; au[s][1] += aw[s] * v1;
      au[s][2] += aw[s] * v2; au[s][3] += aw[s] * v3;
    }
  }
#pragma unroll
  for (int s = 0; s < 8; ++s)
    *(float4*)&red[wave * 2048 + s * 256 + lane * 4] = make_float4(au[s][0], au[s][1], au[s][2], au[s][3]);
  __syncthreads();
#pragma unroll
  for (int i = 0; i < 8; ++i) {
    int idx = tid + i * 256;
    float sum = red[idx] + red[2048 + idx] + red[4096 + idx] + red[6144 + idx];
    upd_part[((long)(b * 16 + jt)) * 2048 + idx] = sum;
  }
}

// ---------------- upd_reduce ----------------
__global__ __launch_bounds__(256) void upd_reduce(
    const float* __restrict__ upd_part, const float* __restrict__ asum_part,
    unsigned short* __restrict__ updb) {
  const int bx = blockIdx.x;
  const int b = bx >> 3, s = bx & 7;
  const int tid = threadIdx.x;
  float as = 0.f;
#pragma unroll
  for (int jt = 0; jt < 16; ++jt) as += asum_part[((long)(b * 16 + jt)) * 8 + s];
  float sum = 0.f;
#pragma unroll
  for (int jt = 0; jt < 16; ++jt)
    sum += upd_part[((long)(b * 16 + jt)) * 2048 + s * 256 + tid];
  updb[((long)b * 8 + s) * 256 + tid] = f2b(sum / as);
}

// ---------------- gigh: grid (8,3,2) ----------------
__global__ __launch_bounds__(256) void gigh(
    const unsigned short* __restrict__ updb, const unsigned short* __restrict__ sbf,
    const unsigned short* __restrict__ Wih, const unsigned short* __restrict__ Whh,
    const float* __restrict__ bih, const float* __restrict__ bhh,
    float* __restrict__ gib, float* __restrict__ ghb) {
  const unsigned short* X = blockIdx.z ? sbf : updb;
  const unsigned short* W = blockIdx.z ? Whh : Wih;
  const float* bias = blockIdx.z ? bhh : bih;
  float* Y = blockIdx.z ? ghb : gib;
  __shared__ unsigned short Xs[64 * 264];
  const int tid = threadIdx.x;
  const int m0 = blockIdx.x * 64;
  const int n_base = blockIdx.y * 256;
#pragma unroll
  for (int i = 0; i < 8; ++i) {
    int c = tid + i * 256;
    int row = c >> 5, seg = c & 31;
    *(ushort8*)&Xs[row * 264 + seg * 8] = *(const ushort8*)(X + (long)(m0 + row) * 256 + seg * 8);
  }
  __syncthreads();
  const int wave = tid >> 6, lane = tid & 63;
  const int lrow = lane & 15, kgrp = lane >> 4;
  short8 a[8];
#pragma unroll
  for (int kc = 0; kc < 8; ++kc)
    a[kc] = *(const short8*)&Xs[(wave * 16 + lrow) * 264 + kc * 32 + kgrp * 8];
#pragma unroll 2
  for (int nt = 0; nt < 16; ++nt) {
    const int n = n_base + nt * 16 + lrow;
    const unsigned short* wp = W + (long)n * 256 + kgrp * 8;
    f32x4 acc = {0.f, 0.f, 0.f, 0.f};
#pragma unroll
    for (int kc = 0; kc < 8; ++kc)
      acc = __builtin_amdgcn_mfma_f32_16x16x32_bf16(a[kc], *(const short8*)(wp + kc * 32), acc, 0, 0, 0);
    float bn = bias[n];
#pragma unroll
    for (int r = 0; r < 4; ++r) {
      int m = m0 + wave * 16 + kgrp * 4 + r;
      Y[(long)m * 768 + n] = acc[r] + bn;
    }
  }
}

// ---------------- GRU gates + LN(g_ff) fused ----------------
__global__ __launch_bounds__(256) void gru_ln(const float* __restrict__ gi, const float* __restrict__ gh,
                                              const float* __restrict__ slots,
                                              const float* __restrict__ gff, const float* __restrict__ bff,
                                              float* __restrict__ ns, unsigned short* __restrict__ ffl) {
  const int tid = threadIdx.x, lane = tid & 63;
  const long row = (long)blockIdx.x * 4 + (tid >> 6);
  const int d = lane * 4;
  float4 i1 = *(const float4*)(gi + row * 768 + d);
  float4 i2 = *(const float4*)(gi + row * 768 + 256 + d);
  float4 i3 = *(const float4*)(gi + row * 768 + 512 + d);
  float4 h1 = *(const float4*)(gh + row * 768 + d);
  float4 h2 = *(const float4*)(gh + row * 768 + 256 + d);
  float4 h3 = *(const float4*)(gh + row * 768 + 512 + d);
  float4 sl = *(const float4*)(slots + row * 256 + d);
  float n4[4];
  float r, z, nn;
  r = 1.f / (1.f + expf(-(i1.x + h1.x))); z = 1.f / (1.f + expf(-(i2.x + h2.x)));
  nn = tanhf(i3.x + r * h3.x); n4[0] = (1.f - z) * nn + z * sl.x;
  r = 1.f / (1.f + expf(-(i1.y + h1.y))); z = 1.f / (1.f + expf(-(i2.y + h2.y)));
  nn = tanhf(i3.y + r * h3.y); n4[1] = (1.f - z) * nn + z * sl.y;
  r = 1.f / (1.f + expf(-(i1.z + h1.z))); z = 1.f / (1.f + expf(-(i2.z + h2.z)));
  nn = tanhf(i3.z + r * h3.z); n4[2] = (1.f - z) * nn + z * sl.z;
  r = 1.f / (1.f + expf(-(i1.w + h1.w))); z = 1.f / (1.f + expf(-(i2.w + h2.w)));
  nn = tanhf(i3.w + r * h3.w); n4[3] = (1.f - z) * nn + z * sl.w;
  *(float4*)(ns + row * 256 + d) = make_float4(n4[0], n4[1], n4[2], n4[3]);
  float s = n4[0] + n4[1] + n4[2] + n4[3];
  float q = n4[0] * n4[0] + n4[1] * n4[1] + n4[2] * n4[2] + n4[3] * n4[3];
  for (int off = 32; off; off >>= 1) { s += __shfl_xor(s, off); q += __shfl_xor(q, off); }
  float m = s * (1.f / 256.f);
  float inv = rsqrtf(q * (1.f / 256.f) - m * m + 1e-5f);
  float4 gv = *(const float4*)(gff + d);
  float4 bv = *(const float4*)(bff + d);
  ushort4v y;
  y[0] = f2b((n4[0] - m) * inv * gv.x + bv.x);
  y[1] = f2b((n4[1] - m) * inv * gv.y + bv.y);
  y[2] = f2b((n4[2] - m) * inv * gv.z + bv.z);
  y[3] = f2b((n4[3] - m) * inv * gv.w + bv.w);
  *(ushort4v*)(ffl + row * 256 + d) = y;
}

// ---------------- ff12 ----------------
__global__ __launch_bounds__(256) void ff12(
    const unsigned short* __restrict__ ffl,
    const unsigned short* __restrict__ Wf1, const float* __restrict__ bf1,
    const unsigned short* __restrict__ Wf2, const float* __restrict__ bf2,
    const float* __restrict__ nsb, float* __restrict__ slots) {
  __shared__ unsigned short Xs[64 * 264];
  __shared__ unsigned short Hs[64 * 264];
  const int tid = threadIdx.x;
  const int m0 = blockIdx.x * 64;
#pragma unroll
  for (int i = 0; i < 8; ++i) {
    int c = tid + i * 256;
    int row = c >> 5, seg = c & 31;
    *(ushort8*)&Xs[row * 264 + seg * 8] = *(const ushort8*)(ffl + (long)(m0 + row) * 256 + seg * 8);
  }
  __syncthreads();
  const int wave = tid >> 6, lane = tid & 63;
  const int lrow = lane & 15, kgrp = lane >> 4;
  short8 a[8];
#pragma unroll
  for (int kc = 0; kc < 8; ++kc)
    a[kc] = *(const short8*)&Xs[(wave * 16 + lrow) * 264 + kc * 32 + kgrp * 8];
#pragma unroll 2
  for (int nt = 0; nt < 16; ++nt) {
    const int n = nt * 16 + lrow;
    const unsigned short* wp = Wf1 + (long)n * 256 + kgrp * 8;
    f32x4 acc = {0.f, 0.f, 0.f, 0.f};
#pragma unroll
    for (int kc = 0; kc < 8; ++kc)
      acc = __builtin_amdgcn_mfma_f32_16x16x32_bf16(a[kc], *(const short8*)(wp + kc * 32), acc, 0, 0, 0);
    float bn = bf1[n];
#pragma unroll
    for (int r = 0; r < 4; ++r)
      Hs[(wave * 16 + kgrp * 4 + r) * 264 + n] = f2b(fmaxf(acc[r] + bn, 0.f));
  }
  __syncthreads();
  short8 h[8];
#pragma unroll
  for (int kc = 0; kc < 8; ++kc)
    h[kc] = *(const short8*)&Hs[(wave * 16 + lrow) * 264 + kc * 32 + kgrp * 8];
#pragma unroll 2
  for (int nt = 0; nt < 16; ++nt) {
    const int n = nt * 16 + lrow;
    const unsigned short* wp = Wf2 + (long)n * 256 + kgrp * 8;
    f32x4 acc = {0.f, 0.f, 0.f, 0.f};
#pragma unroll
    for (int kc = 0; kc < 8; ++kc)
      acc = __builtin_amdgcn_mfma_f32_16x16x32_bf16(h[kc], *(const short8*)(wp + kc * 32), acc, 0, 0, 0);
    float bn = bf2[n];
#pragma unroll
    for (int r = 0; r < 4; ++r) {
      int m = m0 + wave * 16 + kgrp * 4 + r;
      slots[(long)m * 256 + n] = acc[r] + bn + nsb[(long)m * 256 + n];
    }
  }
}

// ---------------- output ----------------
__global__ __launch_bounds__(256) void write_out(const float* __restrict__ slots, const int* __restrict__ flag,
                                                 void* __restrict__ out) {
  long i = (long)blockIdx.x * 256 + threadIdx.x;
  float v = slots[i];
  if (*flag) ((__hip_bfloat16*)out)[i] = __float2bfloat16(v);
  else ((float*)out)[i] = v;
}

// ---------------- host ----------------
extern "C" void kernel_launch(void* const* d_in, const int* in_sizes, int n_in,
                              void* d_out, int out_size, void* d_ws, size_t ws_size,
                              hipStream_t stream) {
  (void)in_sizes; (void)n_in; (void)out_size; (void)ws_size;
  float* wsf = (float*)d_ws;
  long o = 0;
  float* conv = wsf; o += kConvTotal;
  unsigned short* wbf = (unsigned short*)(wsf + o); o += kWTotal / 2;
  unsigned short* A   = (unsigned short*)(wsf + o); o += (long)BB * NTOKN * DIMN / 2;
  unsigned short* X1  = (unsigned short*)(wsf + o); o += (long)BB * NTOKN * DIMN / 2;
  unsigned short* X2  = (unsigned short*)(wsf + o); o += (long)BB * NTOKN * DIMN / 2;
  unsigned short* Kb  = (unsigned short*)(wsf + o); o += (long)BB * NTOKN * DIMN / 2;
  unsigned short* Vb  = (unsigned short*)(wsf + o); o += (long)BB * NTOKN * DIMN / 2;
  float* slots = wsf + o; o += 131072;
  unsigned short* sbf = (unsigned short*)(wsf + o); o += 65536;   // 512x256 bf16 = 65536 floats (FIXED)
  unsigned short* qb  = (unsigned short*)(wsf + o); o += 65536;   // FIXED
  float* upd_part = wsf + o; o += 2097152;   // [64][16][8][256]
  float* asum_part = wsf + o; o += 8192;     // [64][16][8]
  unsigned short* updb = (unsigned short*)(wsf + o); o += 65536;  // FIXED
  float* gib   = wsf + o; o += 393216;
  float* ghb   = wsf + o; o += 393216;
  float* nsb   = wsf + o; o += 131072;
  unsigned short* ffl  = (unsigned short*)(wsf + o); o += 65536;  // FIXED
  float* partials = wsf + o; o += 2048;
  float* stats = wsf + o; o += 128;
  int* flag = (int*)(wsf + o); o += 16;

  long coff[kNConv];
  { long acc = 0; for (int i = 0; i < kNConv; ++i) { coff[i] = acc; acc += kConvSizes[i]; } }
  const float* noise_f = conv + coff[0];
  const float* Wpos = conv + coff[1];
  const float* bpos = conv + coff[2];
  const float* genc = conv + coff[3];
  const float* benc = conv + coff[4];
  const float* bm1  = conv + coff[6];
  const float* bm2  = conv + coff[8];
  const float* gin  = conv + coff[9];
  const float* bin  = conv + coff[10];
  const float* bq   = conv + coff[12];
  const float* bk   = conv + coff[14];
  const float* bv   = conv + coff[16];
  const float* bih  = conv + coff[19];
  const float* bhh  = conv + coff[20];
  const float* gs   = conv + coff[21];
  const float* bs   = conv + coff[22];
  const float* gff  = conv + coff[23];
  const float* bff  = conv + coff[24];
  const float* bf1  = conv + coff[26];
  const float* bf2  = conv + coff[28];
  const float* mu   = conv + coff[29];
  const float* sigma = conv + coff[30];

  const unsigned short* Wm1b = wbf;
  const unsigned short* Wm2b = wbf + 65536;
  const unsigned short* Wqb  = wbf + 131072;
  const unsigned short* Wkb  = wbf + 196608;
  const unsigned short* Wvb  = wbf + 262144;
  const unsigned short* Wihb = wbf + 327680;
  const unsigned short* Whhb = wbf + 524288;
  const unsigned short* Wf1b = wbf + 720896;
  const unsigned short* Wf2b = wbf + 786432;

  detect_dtype<<<1, 1, 0, stream>>>(d_in[10], flag);

  PtrPack pk;
  for (int i = 0; i < kNConv; ++i) pk.p[i] = d_in[i + 1];
  convert_weights<<<(kConvTotal + 255) / 256, 256, 0, stream>>>(pk, flag, conv);
  convert_wbf16<<<(kWTotal + 255) / 256, 256, 0, stream>>>(conv, wbf);

  // encoder
  posembed_stats<<<dim3(16, 64), 256, 0, stream>>>(d_in[0], flag, Wpos, bpos, A, partials);
  stats_reduce<<<1, 64, 0, stream>>>(partials, stats);
  const int MT = BB * NTOKN / 64;  // 1024
  gemm_m1<<<MT, 256, 0, stream>>>(A, stats, genc, benc, Wm1b, bm1, X1);
  gemm_m2ln<<<MT, 256, 0, stream>>>(X1, Wm2b, bm2, gin, bin, X2);
  gemm_kv<<<MT, 256, 0, stream>>>(X2, Wkb, Wvb, bk, bv, Kb, Vb);

  slots_init<<<512, 256, 0, stream>>>(noise_f, mu, sigma, slots);

  for (int it = 0; it < NSTEP; ++it) {
    lnq_q<<<64, 256, 0, stream>>>(slots, gs, bs, Wqb, bq, qb, sbf);
    attn1b<<<dim3(16, 64), 256, 0, stream>>>(qb, Kb, Vb, upd_part, asum_part);
    upd_reduce<<<512, 256, 0, stream>>>(upd_part, asum_part, updb);
    gigh<<<dim3(8, 3, 2), 256, 0, stream>>>(updb, sbf, Wihb, Whhb, bih, bhh, gib, ghb);
    gru_ln<<<128, 256, 0, stream>>>(gib, ghb, slots, gff, bff, nsb, ffl);
    ff12<<<8, 256, 0, stream>>>(ffl, Wf1b, bf1, Wf2b, bf2, nsb, slots);
  }

  write_out<<<512, 256, 0, stream>>>(slots, flag, d_out);
}